// Round 14
// baseline (85.348 us; speedup 1.0000x reference)
//
#include <hip/hip_runtime.h>

#define HW 4096
#define LOG2E 1.44269504088896340736f

typedef _Float16 half8  __attribute__((ext_vector_type(8)));
typedef __bf16   bf16x8 __attribute__((ext_vector_type(8)));
typedef float    f32x16 __attribute__((ext_vector_type(16)));
typedef float    f32x2  __attribute__((ext_vector_type(2)));

// NOTE: __builtin_amdgcn_exp2f is empirically NOT 2^x here (rounds 2/4/5
// failed with identical absmax 3.479065 whenever used). OCML native exp2
// lowers to bare v_exp_f32 and is round-8-proven on this data.
extern "C" __device__ float __ocml_native_exp2_f32(float);
static __device__ __forceinline__ float fexp2(float x) {
    return __ocml_native_exp2_f32(x);
}

static __device__ __forceinline__ unsigned cvtpk_bf16(float lo, float hi) {
    unsigned r;
    asm("v_cvt_pk_bf16_f32 %0, %1, %2" : "=v"(r) : "v"(lo), "v"(hi));
    return r;
}

static __device__ __forceinline__ f32x16 mfma16(uint4 a, uint4 b, f32x16 c) {
    return __builtin_amdgcn_mfma_f32_32x32x16_f16(
        __builtin_bit_cast(half8, a), __builtin_bit_cast(half8, b), c, 0, 0, 0);
}
static __device__ __forceinline__ f32x16 mfmab16(uint4 a, uint4 b, f32x16 c) {
    return __builtin_amdgcn_mfma_f32_32x32x16_bf16(
        __builtin_bit_cast(bf16x8, a), __builtin_bit_cast(bf16x8, b), c, 0, 0, 0);
}

// ---- unified prep: grid (192, 4). UNCHANGED from round 8 (proven). ----
__global__ __launch_bounds__(256) void prep_kernel(
    const float* __restrict__ Fq, const float* __restrict__ Fp,
    const float* __restrict__ W,  const float* __restrict__ bias,
    _Float16* __restrict__ q_ws, char* __restrict__ p_arr, char* __restrict__ v_arr)
{
    const int tid = threadIdx.x;
    const int b   = blockIdx.y;
    const int x   = blockIdx.x;

    if (x >= 64) {
        // ---- V prep: slot (hi,j) <- key 32*mt + 16*chunk + 4*hi + (j&3) + 8*(j>>2) ----
        int mt = x - 64;
        int c5 = tid & 31, hi = (tid >> 5) & 1, chunk = (tid >> 6) & 1, chalf = tid >> 7;
        int c = chalf * 32 + c5;
        int m = mt * 32 + chunk * 16 + hi * 4;
        const float* src = Fp + ((size_t)(b * 64 + c) << 12) + m;
        float4 f0 = *(const float4*)src;        // keys m..m+3   -> j=0..3
        float4 f1 = *(const float4*)(src + 8);  // keys m+8..m+11-> j=4..7
        uint4 o = make_uint4(cvtpk_bf16(f0.x, f0.y), cvtpk_bf16(f0.z, f0.w),
                             cvtpk_bf16(f1.x, f1.y), cvtpk_bf16(f1.z, f1.w));
        size_t tb = ((size_t)(((b * 128 + mt) * 2 + chalf) * 2 + chunk)) << 10;
        *(uint4*)(v_arr + tb + (size_t)((hi << 5) | c5) * 16) = o;
        return;
    }

    // ---- projection, c-split-2 ----
    __shared__ float Wt[64][36];
    __shared__ float comb[128][33];

    for (int i = tid; i < 2048; i += 256)
        Wt[i & 63][i >> 6] = W[i];
    __syncthreads();

    const int isP   = x >> 5;
    const int nl    = tid & 127;
    const int chalf = tid >> 7;
    const int n     = ((x & 31) << 7) + nl;
    const float* in = (isP ? Fp : Fq) + (size_t)(b * 64 + chalf * 32) * HW + n;

    float acc[32];
    #pragma unroll
    for (int o = 0; o < 32; ++o) acc[o] = 0.f;

    for (int c = 0; c < 32; ++c) {
        float f = in[(size_t)c * HW];
        const float* wr = &Wt[chalf * 32 + c][0];
        #pragma unroll
        for (int o = 0; o < 32; o += 4) {
            float4 w4 = *(const float4*)(wr + o);
            acc[o]   += w4.x * f; acc[o+1] += w4.y * f;
            acc[o+2] += w4.z * f; acc[o+3] += w4.w * f;
        }
    }

    if (chalf) {
        #pragma unroll
        for (int o = 0; o < 32; ++o) comb[nl][o] = acc[o];
    }
    __syncthreads();
    if (chalf) return;

    #pragma unroll
    for (int o = 0; o < 32; ++o) acc[o] += comb[nl][o] + bias[o];

    if (!isP) {
        _Float16* dst = q_ws + ((size_t)(b * HW + n) << 5);
        #pragma unroll
        for (int g = 0; g < 4; ++g) {
            union { _Float16 h[8]; uint4 u; } pk;
            #pragma unroll
            for (int j = 0; j < 8; ++j) pk.h[j] = (_Float16)(acc[g * 8 + j] * LOG2E);
            *(uint4*)(dst + g * 8) = pk.u;
        }
    } else {
        int kt = n >> 5, ln = n & 31;
        #pragma unroll
        for (int chunk = 0; chunk < 2; ++chunk) {
            #pragma unroll
            for (int h2 = 0; h2 < 2; ++h2) {
                union { _Float16 h[8]; uint4 u; } pk;
                #pragma unroll
                for (int j = 0; j < 8; ++j) pk.h[j] = (_Float16)acc[chunk * 16 + h2 * 8 + j];
                size_t off = (((size_t)((b * 128 + kt) * 2 + chunk)) << 9) + (size_t)((h2 << 5) + ln) * 8;
                *(uint4*)(p_arr + off * 2) = pk.u;
            }
        }
    }
}

// A-fragment slot (hi,j) holds key kappa(hi,j) = 4hi + (j&3) + 8*(j>>2) =
// the QK^T C-output key order; V prepped with the same map (bijection).
#define SOFTPART(S, A0, A1, LV) { \
    float e0=fexp2(S[0]),  e1=fexp2(S[1]),  e2=fexp2(S[2]),  e3=fexp2(S[3]); \
    float e4=fexp2(S[4]),  e5=fexp2(S[5]),  e6=fexp2(S[6]),  e7=fexp2(S[7]); \
    float e8=fexp2(S[8]),  e9=fexp2(S[9]),  e10=fexp2(S[10]), e11=fexp2(S[11]); \
    float e12=fexp2(S[12]), e13=fexp2(S[13]), e14=fexp2(S[14]), e15=fexp2(S[15]); \
    f32x2 t0 = (f32x2){e0,e1}   + (f32x2){e2,e3}; \
    f32x2 t1 = (f32x2){e4,e5}   + (f32x2){e6,e7}; \
    f32x2 t2 = (f32x2){e8,e9}   + (f32x2){e10,e11}; \
    f32x2 t3 = (f32x2){e12,e13} + (f32x2){e14,e15}; \
    LV += (t0 + t1) + (t2 + t3); \
    A0 = make_uint4(cvtpk_bf16(e0,e1),  cvtpk_bf16(e2,e3),  cvtpk_bf16(e4,e5),  cvtpk_bf16(e6,e7)); \
    A1 = make_uint4(cvtpk_bf16(e8,e9),  cvtpk_bf16(e10,e11), cvtpk_bf16(e12,e13), cvtpk_bf16(e14,e15)); \
}

#define TILE(P0,P1,V00,V01,V10,V11) { \
    f32x16 s0 = (f32x16)0.0f, s1 = (f32x16)0.0f; \
    s0 = mfma16(P0, q00, s0); s0 = mfma16(P1, q01, s0); \
    s1 = mfma16(P0, q10, s1); s1 = mfma16(P1, q11, s1); \
    uint4 A0, A1, B0, B1; \
    SOFTPART(s0, A0, A1, l0v) \
    SOFTPART(s1, B0, B1, l1v) \
    __builtin_amdgcn_s_setprio(1); \
    o00 = mfmab16(A0, V00, o00); o00 = mfmab16(A1, V01, o00); \
    o01 = mfmab16(A0, V10, o01); o01 = mfmab16(A1, V11, o01); \
    o10 = mfmab16(B0, V00, o10); o10 = mfmab16(B1, V01, o10); \
    o11 = mfmab16(B0, V10, o11); o11 = mfmab16(B1, V11, o11); \
    __builtin_amdgcn_s_setprio(0); \
}

// 16 waves/block = 4 waves/SIMD (r12: 2 waves/SIMD left ~26% dual-idle).
// Same grid/per-block traffic/double-buffer as round 8; keys split 16 ways.
// LDS FIX vs r13 crash: part is 8 slots (33.8 KB) with two-phase combine —
// waves 0-7 write, sync, waves 8-15 add, sync, tree-reduce 8. Total ~42 KB
// < the 64 KB per-workgroup limit (r13's part[16] was 76 KB -> launch abort).
__global__ __launch_bounds__(1024, 4) void attn_kernel(
    const _Float16* __restrict__ q_ws, const char* __restrict__ p_arr,
    const char* __restrict__ v_arr, float* __restrict__ out)
{
    __shared__ float part[8][32][33];
    __shared__ float l_red[16][2][64];
    __shared__ float l_inv[64];

    const int tid  = threadIdx.x;
    const int lane = tid & 63;
    const int w    = tid >> 6;       // wave = key split (256 keys each), 0..15
    const int lo5  = lane & 31;
    const int hi   = lane >> 5;

    // XCD-aware swizzle: id%8 = XCD (m09); XCD pair {2b,2b+1} <- batch b.
    // Bijective: id bits [0]|[3:7] -> q-tile, bits [1:2] -> batch.
    const int id   = blockIdx.x + (blockIdx.y << 6);
    const int b    = (id >> 1) & 3;
    const int qb   = (((id >> 3) << 1) | (id & 1)) << 6;

    // Q fragments: 2 q-subtiles x 2 k-chunks, hoisted
    uint4 q00, q01, q10, q11;
    {
        const _Float16* qp = q_ws + (((size_t)(b * HW) + qb + lo5) << 5) + (hi << 3);
        q00 = *(const uint4*)qp;
        q01 = *(const uint4*)(qp + 16);
        q10 = *(const uint4*)(qp + 1024);
        q11 = *(const uint4*)(qp + 1040);
    }

    const char* pb = p_arr + ((size_t)(b * 128 + w * 8) << 11) + (lane << 4);
    const char* vb = v_arr + ((size_t)(b * 128 + w * 8) << 12) + (lane << 4);

    f32x16 o00 = (f32x16)0.0f, o01 = (f32x16)0.0f, o10 = (f32x16)0.0f, o11 = (f32x16)0.0f;
    f32x2 l0v = (f32x2){0.f, 0.f}, l1v = (f32x2){0.f, 0.f};

    uint4 pA0, pA1, vA00, vA01, vA10, vA11;
    uint4 pB0, pB1, vB00, vB01, vB10, vB11;

#define LOADT(P0,P1,V00,V01,V10,V11,T) { \
    const char* pp = pb + ((size_t)(T) << 11); \
    P0 = *(const uint4*)pp; P1 = *(const uint4*)(pp + 1024); \
    const char* vp = vb + ((size_t)(T) << 12); \
    V00 = *(const uint4*)vp;          V01 = *(const uint4*)(vp + 1024); \
    V10 = *(const uint4*)(vp + 2048); V11 = *(const uint4*)(vp + 3072); }

    LOADT(pA0, pA1, vA00, vA01, vA10, vA11, 0)
    for (int i = 0; i < 4; ++i) {
        int t = 2 * i + 1;
        LOADT(pB0, pB1, vB00, vB01, vB10, vB11, t)
        TILE(pA0, pA1, vA00, vA01, vA10, vA11)
        int t2 = (t + 1 > 7) ? 7 : (t + 1);
        LOADT(pA0, pA1, vA00, vA01, vA10, vA11, t2)
        TILE(pB0, pB1, vB00, vB01, vB10, vB11)
    }

    // ---- epilogue: combine 16 key-split waves ----
    l_red[w][0][lane] = l0v.x + l0v.y;
    l_red[w][1][lane] = l1v.x + l1v.y;
    __syncthreads();
    if (tid < 64) {
        int s_ = tid >> 5, qq = tid & 31;
        float sum = 0.f;
        #pragma unroll
        for (int w2 = 0; w2 < 16; ++w2)
            sum += l_red[w2][s_][qq] + l_red[w2][s_][qq + 32];
        l_inv[tid] = 1.0f / sum;
    }

#define EPIPASS(OC, S_, H_) { \
    __syncthreads(); \
    if (w < 8) { \
        _Pragma("unroll") \
        for (int r = 0; r < 16; ++r) \
            part[w][(r & 3) + 8 * (r >> 2) + 4 * hi][lo5] = OC[r]; \
    } \
    __syncthreads(); \
    if (w >= 8) { \
        _Pragma("unroll") \
        for (int r = 0; r < 16; ++r) \
            part[w - 8][(r & 3) + 8 * (r >> 2) + 4 * hi][lo5] += OC[r]; \
    } \
    __syncthreads(); \
    { \
        int c_ = tid >> 5, q_ = tid & 31; \
        float v_ = ((part[0][q_][c_] + part[1][q_][c_]) + (part[2][q_][c_] + part[3][q_][c_])) \
                 + ((part[4][q_][c_] + part[5][q_][c_]) + (part[6][q_][c_] + part[7][q_][c_])); \
        out[((size_t)(((b << 6) + ((H_) << 5) + c_)) << 12) + qb + ((S_) << 5) + q_] = v_ * l_inv[((S_) << 5) + q_]; \
    } \
}

    EPIPASS(o00, 0, 0)
    EPIPASS(o01, 0, 1)
    EPIPASS(o10, 1, 0)
    EPIPASS(o11, 1, 1)
}

extern "C" void kernel_launch(void* const* d_in, const int* in_sizes, int n_in,
                              void* d_out, int out_size, void* d_ws, size_t ws_size,
                              hipStream_t stream)
{
    const float* Fq = (const float*)d_in[0];
    const float* Fp = (const float*)d_in[1];
    const float* W  = (const float*)d_in[2];
    const float* bs = (const float*)d_in[3];
    float* out = (float*)d_out;

    _Float16* q_ws = (_Float16*)d_ws;               // 1 MB
    char* p_arr = (char*)d_ws + (1 << 20);          // 1 MB
    char* v_arr = (char*)d_ws + (2 << 20);          // 2 MB

    prep_kernel<<<dim3(192, 4), 256, 0, stream>>>(Fq, Fp, W, bs, q_ws, p_arr, v_arr);
    attn_kernel<<<dim3(64, 4), 1024, 0, stream>>>(q_ws, p_arr, v_arr, out);
}

// Round 15
// 30.509 us; speedup vs baseline: 2.7975x; 2.7975x over previous
//
#include <hip/hip_runtime.h>

#define HW 4096
#define LOG2E 1.44269504088896340736f

typedef _Float16 half8  __attribute__((ext_vector_type(8)));
typedef __bf16   bf16x8 __attribute__((ext_vector_type(8)));
typedef float    f32x16 __attribute__((ext_vector_type(16)));
typedef float    f32x2  __attribute__((ext_vector_type(2)));

// NOTE: __builtin_amdgcn_exp2f is empirically NOT 2^x here (rounds 2/4/5
// failed with identical absmax 3.479065 whenever used). OCML native exp2
// lowers to bare v_exp_f32 and is round-8-proven on this data.
extern "C" __device__ float __ocml_native_exp2_f32(float);
static __device__ __forceinline__ float fexp2(float x) {
    return __ocml_native_exp2_f32(x);
}

static __device__ __forceinline__ unsigned cvtpk_bf16(float lo, float hi) {
    unsigned r;
    asm("v_cvt_pk_bf16_f32 %0, %1, %2" : "=v"(r) : "v"(lo), "v"(hi));
    return r;
}

static __device__ __forceinline__ f32x16 mfma16(uint4 a, uint4 b, f32x16 c) {
    return __builtin_amdgcn_mfma_f32_32x32x16_f16(
        __builtin_bit_cast(half8, a), __builtin_bit_cast(half8, b), c, 0, 0, 0);
}
static __device__ __forceinline__ f32x16 mfmab16(uint4 a, uint4 b, f32x16 c) {
    return __builtin_amdgcn_mfma_f32_32x32x16_bf16(
        __builtin_bit_cast(bf16x8, a), __builtin_bit_cast(bf16x8, b), c, 0, 0, 0);
}

// ---- unified prep: grid (192, 4). UNCHANGED from round 8 (proven). ----
__global__ __launch_bounds__(256) void prep_kernel(
    const float* __restrict__ Fq, const float* __restrict__ Fp,
    const float* __restrict__ W,  const float* __restrict__ bias,
    _Float16* __restrict__ q_ws, char* __restrict__ p_arr, char* __restrict__ v_arr)
{
    const int tid = threadIdx.x;
    const int b   = blockIdx.y;
    const int x   = blockIdx.x;

    if (x >= 64) {
        // ---- V prep: slot (hi,j) <- key 32*mt + 16*chunk + 4*hi + (j&3) + 8*(j>>2) ----
        int mt = x - 64;
        int c5 = tid & 31, hi = (tid >> 5) & 1, chunk = (tid >> 6) & 1, chalf = tid >> 7;
        int c = chalf * 32 + c5;
        int m = mt * 32 + chunk * 16 + hi * 4;
        const float* src = Fp + ((size_t)(b * 64 + c) << 12) + m;
        float4 f0 = *(const float4*)src;        // keys m..m+3   -> j=0..3
        float4 f1 = *(const float4*)(src + 8);  // keys m+8..m+11-> j=4..7
        uint4 o = make_uint4(cvtpk_bf16(f0.x, f0.y), cvtpk_bf16(f0.z, f0.w),
                             cvtpk_bf16(f1.x, f1.y), cvtpk_bf16(f1.z, f1.w));
        size_t tb = ((size_t)(((b * 128 + mt) * 2 + chalf) * 2 + chunk)) << 10;
        *(uint4*)(v_arr + tb + (size_t)((hi << 5) | c5) * 16) = o;
        return;
    }

    // ---- projection, c-split-2 ----
    __shared__ float Wt[64][36];
    __shared__ float comb[128][33];

    for (int i = tid; i < 2048; i += 256)
        Wt[i & 63][i >> 6] = W[i];
    __syncthreads();

    const int isP   = x >> 5;
    const int nl    = tid & 127;
    const int chalf = tid >> 7;
    const int n     = ((x & 31) << 7) + nl;
    const float* in = (isP ? Fp : Fq) + (size_t)(b * 64 + chalf * 32) * HW + n;

    float acc[32];
    #pragma unroll
    for (int o = 0; o < 32; ++o) acc[o] = 0.f;

    for (int c = 0; c < 32; ++c) {
        float f = in[(size_t)c * HW];
        const float* wr = &Wt[chalf * 32 + c][0];
        #pragma unroll
        for (int o = 0; o < 32; o += 4) {
            float4 w4 = *(const float4*)(wr + o);
            acc[o]   += w4.x * f; acc[o+1] += w4.y * f;
            acc[o+2] += w4.z * f; acc[o+3] += w4.w * f;
        }
    }

    if (chalf) {
        #pragma unroll
        for (int o = 0; o < 32; ++o) comb[nl][o] = acc[o];
    }
    __syncthreads();
    if (chalf) return;

    #pragma unroll
    for (int o = 0; o < 32; ++o) acc[o] += comb[nl][o] + bias[o];

    if (!isP) {
        _Float16* dst = q_ws + ((size_t)(b * HW + n) << 5);
        #pragma unroll
        for (int g = 0; g < 4; ++g) {
            union { _Float16 h[8]; uint4 u; } pk;
            #pragma unroll
            for (int j = 0; j < 8; ++j) pk.h[j] = (_Float16)(acc[g * 8 + j] * LOG2E);
            *(uint4*)(dst + g * 8) = pk.u;
        }
    } else {
        int kt = n >> 5, ln = n & 31;
        #pragma unroll
        for (int chunk = 0; chunk < 2; ++chunk) {
            #pragma unroll
            for (int h2 = 0; h2 < 2; ++h2) {
                union { _Float16 h[8]; uint4 u; } pk;
                #pragma unroll
                for (int j = 0; j < 8; ++j) pk.h[j] = (_Float16)acc[chunk * 16 + h2 * 8 + j];
                size_t off = (((size_t)((b * 128 + kt) * 2 + chunk)) << 9) + (size_t)((h2 << 5) + ln) * 8;
                *(uint4*)(p_arr + off * 2) = pk.u;
            }
        }
    }
}

// A-fragment slot (hi,j) holds key kappa(hi,j) = 4hi + (j&3) + 8*(j>>2) =
// the QK^T C-output key order; V prepped with the same map (bijection).
#define SOFTPART(S, A0, A1, LV) { \
    float e0=fexp2(S[0]),  e1=fexp2(S[1]),  e2=fexp2(S[2]),  e3=fexp2(S[3]); \
    float e4=fexp2(S[4]),  e5=fexp2(S[5]),  e6=fexp2(S[6]),  e7=fexp2(S[7]); \
    float e8=fexp2(S[8]),  e9=fexp2(S[9]),  e10=fexp2(S[10]), e11=fexp2(S[11]); \
    float e12=fexp2(S[12]), e13=fexp2(S[13]), e14=fexp2(S[14]), e15=fexp2(S[15]); \
    f32x2 t0 = (f32x2){e0,e1}   + (f32x2){e2,e3}; \
    f32x2 t1 = (f32x2){e4,e5}   + (f32x2){e6,e7}; \
    f32x2 t2 = (f32x2){e8,e9}   + (f32x2){e10,e11}; \
    f32x2 t3 = (f32x2){e12,e13} + (f32x2){e14,e15}; \
    LV += (t0 + t1) + (t2 + t3); \
    A0 = make_uint4(cvtpk_bf16(e0,e1),  cvtpk_bf16(e2,e3),  cvtpk_bf16(e4,e5),  cvtpk_bf16(e6,e7)); \
    A1 = make_uint4(cvtpk_bf16(e8,e9),  cvtpk_bf16(e10,e11), cvtpk_bf16(e12,e13), cvtpk_bf16(e14,e15)); \
}

// ---- software-pipelined tile phases ----
// QKPART(t+1) is issued BEFORE SOFTPV(t): the 4 QK MFMAs' results are not
// needed until the NEXT iteration, so the MFMA pipe runs them concurrently
// with SOFT's VALU/trans work (r12: 26% of cycles had neither pipe issuing).
#define QKPART(S0, S1, P0, P1) { \
    S0 = (f32x16)0.0f; S1 = (f32x16)0.0f; \
    S0 = mfma16(P0, q00, S0); S0 = mfma16(P1, q01, S0); \
    S1 = mfma16(P0, q10, S1); S1 = mfma16(P1, q11, S1); \
}

#define SOFTPV(S0, S1, V00, V01, V10, V11) { \
    uint4 A0, A1, B0, B1; \
    SOFTPART(S0, A0, A1, l0v) \
    SOFTPART(S1, B0, B1, l1v) \
    __builtin_amdgcn_s_setprio(1); \
    o00 = mfmab16(A0, V00, o00); o00 = mfmab16(A1, V01, o00); \
    o01 = mfmab16(A0, V10, o01); o01 = mfmab16(A1, V11, o01); \
    o10 = mfmab16(B0, V00, o10); o10 = mfmab16(B1, V01, o10); \
    o11 = mfmab16(B0, V10, o11); o11 = mfmab16(B1, V11, o11); \
    __builtin_amdgcn_s_setprio(0); \
}

__global__ __launch_bounds__(512, 2) void attn_kernel(
    const _Float16* __restrict__ q_ws, const char* __restrict__ p_arr,
    const char* __restrict__ v_arr, float* __restrict__ out)
{
    __shared__ float part[8][32][33];
    __shared__ float l_red[8][2][64];
    __shared__ float l_inv[64];

    const int tid  = threadIdx.x;
    const int lane = tid & 63;
    const int w    = tid >> 6;       // wave = key split (512 keys each)
    const int lo5  = lane & 31;
    const int hi   = lane >> 5;

    // XCD-aware swizzle: id%8 = XCD (m09); XCD pair {2b,2b+1} <- batch b.
    // Bijective: id bits [0]|[3:7] -> q-tile, bits [1:2] -> batch.
    const int id   = blockIdx.x + (blockIdx.y << 6);
    const int b    = (id >> 1) & 3;
    const int qb   = (((id >> 3) << 1) | (id & 1)) << 6;

    // Q fragments: 2 q-subtiles x 2 k-chunks, hoisted
    uint4 q00, q01, q10, q11;
    {
        const _Float16* qp = q_ws + (((size_t)(b * HW) + qb + lo5) << 5) + (hi << 3);
        q00 = *(const uint4*)qp;
        q01 = *(const uint4*)(qp + 16);
        q10 = *(const uint4*)(qp + 1024);
        q11 = *(const uint4*)(qp + 1040);
    }

    const char* pb = p_arr + ((size_t)(b * 128 + w * 16) << 11) + (lane << 4);
    const char* vb = v_arr + ((size_t)(b * 128 + w * 16) << 12) + (lane << 4);

    f32x16 o00 = (f32x16)0.0f, o01 = (f32x16)0.0f, o10 = (f32x16)0.0f, o11 = (f32x16)0.0f;
    f32x2 l0v = (f32x2){0.f, 0.f}, l1v = (f32x2){0.f, 0.f};

    uint4 pA0, pA1, vA00, vA01, vA10, vA11;
    uint4 pB0, pB1, vB00, vB01, vB10, vB11;
    f32x16 sA0, sA1, sB0, sB1;

#define LOADT(P0,P1,V00,V01,V10,V11,T) { \
    const char* pp = pb + ((size_t)(T) << 11); \
    P0 = *(const uint4*)pp; P1 = *(const uint4*)(pp + 1024); \
    const char* vp = vb + ((size_t)(T) << 12); \
    V00 = *(const uint4*)vp;          V01 = *(const uint4*)(vp + 1024); \
    V10 = *(const uint4*)(vp + 2048); V11 = *(const uint4*)(vp + 3072); }

    LOADT(pA0, pA1, vA00, vA01, vA10, vA11, 0)
    QKPART(sA0, sA1, pA0, pA1)
    for (int i = 0; i < 7; ++i) {
        int t = 2 * i + 1;
        LOADT(pB0, pB1, vB00, vB01, vB10, vB11, t)
        QKPART(sB0, sB1, pB0, pB1)                       // tile t   (MFMA, result needed next)
        SOFTPV(sA0, sA1, vA00, vA01, vA10, vA11)         // tile t-1 (VALU+PV, overlaps above)
        LOADT(pA0, pA1, vA00, vA01, vA10, vA11, t + 1)
        QKPART(sA0, sA1, pA0, pA1)                       // tile t+1
        SOFTPV(sB0, sB1, vB00, vB01, vB10, vB11)         // tile t
    }
    LOADT(pB0, pB1, vB00, vB01, vB10, vB11, 15)
    QKPART(sB0, sB1, pB0, pB1)
    SOFTPV(sA0, sA1, vA00, vA01, vA10, vA11)             // tile 14
    SOFTPV(sB0, sB1, vB00, vB01, vB10, vB11)             // tile 15

    // ---- epilogue: combine 8 key-split waves ----
    l_red[w][0][lane] = l0v.x + l0v.y;
    l_red[w][1][lane] = l1v.x + l1v.y;
    __syncthreads();
    if (tid < 64) {
        int s_ = tid >> 5, qq = tid & 31;
        float sum = 0.f;
        #pragma unroll
        for (int w2 = 0; w2 < 8; ++w2)
            sum += l_red[w2][s_][qq] + l_red[w2][s_][qq + 32];
        l_inv[tid] = 1.0f / sum;
    }

#define EPIPASS(OC, S_, H_) { \
    __syncthreads(); \
    _Pragma("unroll") \
    for (int r = 0; r < 16; ++r) \
        part[w][(r & 3) + 8 * (r >> 2) + 4 * hi][lo5] = OC[r]; \
    __syncthreads(); \
    _Pragma("unroll") \
    for (int rep = 0; rep < 2; ++rep) { \
        int idx = rep * 512 + tid; \
        int c_ = idx >> 5, q_ = idx & 31; \
        float v_ = ((part[0][q_][c_] + part[1][q_][c_]) + (part[2][q_][c_] + part[3][q_][c_])) \
                 + ((part[4][q_][c_] + part[5][q_][c_]) + (part[6][q_][c_] + part[7][q_][c_])); \
        out[((size_t)(((b << 6) + ((H_) << 5) + c_)) << 12) + qb + ((S_) << 5) + q_] = v_ * l_inv[((S_) << 5) + q_]; \
    } \
}

    EPIPASS(o00, 0, 0)
    EPIPASS(o01, 0, 1)
    EPIPASS(o10, 1, 0)
    EPIPASS(o11, 1, 1)
}

extern "C" void kernel_launch(void* const* d_in, const int* in_sizes, int n_in,
                              void* d_out, int out_size, void* d_ws, size_t ws_size,
                              hipStream_t stream)
{
    const float* Fq = (const float*)d_in[0];
    const float* Fp = (const float*)d_in[1];
    const float* W  = (const float*)d_in[2];
    const float* bs = (const float*)d_in[3];
    float* out = (float*)d_out;

    _Float16* q_ws = (_Float16*)d_ws;               // 1 MB
    char* p_arr = (char*)d_ws + (1 << 20);          // 1 MB
    char* v_arr = (char*)d_ws + (2 << 20);          // 2 MB

    prep_kernel<<<dim3(192, 4), 256, 0, stream>>>(Fq, Fp, W, bs, q_ws, p_arr, v_arr);
    attn_kernel<<<dim3(64, 4), 512, 0, stream>>>(q_ws, p_arr, v_arr, out);
}